// Round 1
// baseline (177.018 us; speedup 1.0000x reference)
//
#include <hip/hip_runtime.h>
#include <math.h>

// Problem constants (from reference)
constexpr int kB  = 8;
constexpr int kNL = 48;
constexpr int kNT = 512;
constexpr int kH  = 128;
constexpr int kG  = 10;

constexpr int kRowsL = kB * kNL;          // 384 ligand rows
constexpr int kRowsT = kB * kNT;          // 4096 protein rows
constexpr int kM     = kB * kNL * kNT;    // 196608 pairs
constexpr float kEps = 1e-5f;

// Output layout (flat concat, reference return order)
constexpr size_t OFF_PI = 0;
constexpr size_t OFF_SG = (size_t)kM * kG;          // 1966080
constexpr size_t OFF_MU = 2 * (size_t)kM * kG;      // 3932160
constexpr size_t OFF_D  = 3 * (size_t)kM * kG;      // 5898240
constexpr size_t OFF_CB = OFF_D + kM;               // 6094848

__device__ __forceinline__ float elu_f(float x) {
    return x > 0.0f ? x : (__expf(x) - 1.0f);
}

// Kernel 1: fold Linear(W1,b1) + BatchNorm affine into per-row precomputed
// activations.  A_l'[r][c] = (lig_s[r]·W1[c] + b1[c] - mean[c])*s[c] + beta[c]
//              A_t'[r][c] = (pro_s[r]·W1[c])*s[c],  s = gamma*rsqrt(var+eps)
// Then pre-ELU activation for pair (l,t) is exactly A_l'[l] + A_t'[t].
__global__ __launch_bounds__(128) void prep_kernel(
    const float* __restrict__ lig_s, const float* __restrict__ pro_s,
    const float* __restrict__ W1,    const float* __restrict__ b1,
    const float* __restrict__ gamma, const float* __restrict__ beta,
    const float* __restrict__ mean,  const float* __restrict__ var,
    float* __restrict__ Al, float* __restrict__ At)
{
    const int r = blockIdx.x;      // 0 .. kRowsL+kRowsT-1
    const int c = threadIdx.x;     // 0 .. 127

    __shared__ float srow[kH];
    const bool is_lig = (r < kRowsL);
    const float* in = is_lig ? (lig_s + (size_t)r * kH)
                             : (pro_s + (size_t)(r - kRowsL) * kH);
    srow[c] = in[c];
    __syncthreads();

    const float4* w4 = (const float4*)(W1 + (size_t)c * kH);
    const float4* x4 = (const float4*)srow;
    float acc = 0.0f;
#pragma unroll
    for (int k = 0; k < kH / 4; ++k) {
        float4 w = w4[k];
        float4 x = x4[k];
        acc += w.x * x.x + w.y * x.y + w.z * x.z + w.w * x.w;
    }

    const float s = gamma[c] * rsqrtf(var[c] + kEps);
    if (is_lig) {
        Al[(size_t)r * kH + c] = (acc + b1[c] - mean[c]) * s + beta[c];
    } else {
        At[(size_t)(r - kRowsL) * kH + c] = acc * s;
    }
}

// Kernel 2: one thread per (l,t) pair. Streams A_t' row as float4 from L2,
// A_l' row + projection weights via wave-uniform loads (-> s_load), keeps 30
// fp32 accumulators in VGPRs. Epilogue: softmax(pi), elu+1.1 (sigma),
// elu+1.0 (mu), pair distance, batch id.
__global__ __launch_bounds__(256) void pair_kernel(
    const float* __restrict__ Al, const float* __restrict__ At,
    const float* __restrict__ Wpi, const float* __restrict__ bpi,
    const float* __restrict__ Wsg, const float* __restrict__ bsg,
    const float* __restrict__ Wmu, const float* __restrict__ bmu,
    const float* __restrict__ lig_pos, const float* __restrict__ pro_pos,
    float* __restrict__ out)
{
    const int tid   = threadIdx.x;
    const int chunk = blockIdx.x & 1;        // two 256-wide t-chunks
    const int bl    = blockIdx.x >> 1;       // 0..383  (= b*48 + l)
    const int b     = bl / kNL;
    const int t     = chunk * 256 + tid;     // 0..511
    const int m     = bl * kNT + t;          // pair index
    const int pr    = b * kNT + t;           // protein row index

    const float4* al4 = (const float4*)(Al + (size_t)bl * kH);  // uniform
    const float4* at4 = (const float4*)(At + (size_t)pr * kH);  // per-thread
    const float4* wp4 = (const float4*)Wpi;
    const float4* ws4 = (const float4*)Wsg;
    const float4* wm4 = (const float4*)Wmu;

    float ap[kG], as_[kG], am[kG];
#pragma unroll
    for (int j = 0; j < kG; ++j) { ap[j] = 0.0f; as_[j] = 0.0f; am[j] = 0.0f; }

    for (int kc = 0; kc < kH / 4; ++kc) {
        float4 a = at4[kc];
        float4 L = al4[kc];
        const float c0 = elu_f(L.x + a.x);
        const float c1 = elu_f(L.y + a.y);
        const float c2 = elu_f(L.z + a.z);
        const float c3 = elu_f(L.w + a.w);
#pragma unroll
        for (int j = 0; j < kG; ++j) {
            float4 w = wp4[j * (kH / 4) + kc];
            ap[j]  += c0 * w.x + c1 * w.y + c2 * w.z + c3 * w.w;
            w = ws4[j * (kH / 4) + kc];
            as_[j] += c0 * w.x + c1 * w.y + c2 * w.z + c3 * w.w;
            w = wm4[j * (kH / 4) + kc];
            am[j]  += c0 * w.x + c1 * w.y + c2 * w.z + c3 * w.w;
        }
    }

    // --- pi: softmax over G logits ---
    float li[kG];
    float mx = -3.4e38f;
#pragma unroll
    for (int j = 0; j < kG; ++j) {
        li[j] = ap[j] + bpi[j];
        mx = fmaxf(mx, li[j]);
    }
    float sum = 0.0f;
#pragma unroll
    for (int j = 0; j < kG; ++j) {
        li[j] = __expf(li[j] - mx);
        sum += li[j];
    }
    const float inv = 1.0f / sum;
    float* opi = out + OFF_PI + (size_t)m * kG;
#pragma unroll
    for (int j = 0; j < kG; ++j) opi[j] = li[j] * inv;

    // --- sigma: elu + 1.1 ---
    float* osg = out + OFF_SG + (size_t)m * kG;
#pragma unroll
    for (int j = 0; j < kG; ++j) osg[j] = elu_f(as_[j] + bsg[j]) + 1.1f;

    // --- mu: elu + 1.0 ---
    float* omu = out + OFF_MU + (size_t)m * kG;
#pragma unroll
    for (int j = 0; j < kG; ++j) omu[j] = elu_f(am[j] + bmu[j]) + 1.0f;

    // --- dist ---
    const float lx = lig_pos[(size_t)bl * 3 + 0];
    const float ly = lig_pos[(size_t)bl * 3 + 1];
    const float lz = lig_pos[(size_t)bl * 3 + 2];
    const float tx = pro_pos[(size_t)pr * 3 + 0];
    const float ty = pro_pos[(size_t)pr * 3 + 1];
    const float tz = pro_pos[(size_t)pr * 3 + 2];
    const float dx = lx - tx, dy = ly - ty, dz = lz - tz;
    out[OFF_D + m] = sqrtf(dx * dx + dy * dy + dz * dz);

    // --- C_batch ---
    out[OFF_CB + m] = (float)b;
}

extern "C" void kernel_launch(void* const* d_in, const int* in_sizes, int n_in,
                              void* d_out, int out_size, void* d_ws, size_t ws_size,
                              hipStream_t stream) {
    (void)in_sizes; (void)n_in; (void)out_size; (void)ws_size;
    const float* lig_s    = (const float*)d_in[0];
    const float* lig_pos  = (const float*)d_in[1];
    // d_in[2] = lig_batch (unused; uniform segments)
    const float* pro_s    = (const float*)d_in[3];
    const float* pro_pos  = (const float*)d_in[4];
    // d_in[5] = pro_batch (unused)
    const float* W1       = (const float*)d_in[6];
    const float* b1       = (const float*)d_in[7];
    const float* bn_gamma = (const float*)d_in[8];
    const float* bn_beta  = (const float*)d_in[9];
    const float* bn_mean  = (const float*)d_in[10];
    const float* bn_var   = (const float*)d_in[11];
    const float* W_pi     = (const float*)d_in[12];
    const float* b_pi     = (const float*)d_in[13];
    const float* W_sigma  = (const float*)d_in[14];
    const float* b_sigma  = (const float*)d_in[15];
    const float* W_mu     = (const float*)d_in[16];
    const float* b_mu     = (const float*)d_in[17];

    float* out = (float*)d_out;
    float* Al  = (float*)d_ws;                        // 384*128 floats
    float* At  = Al + (size_t)kRowsL * kH;            // 4096*128 floats

    prep_kernel<<<kRowsL + kRowsT, 128, 0, stream>>>(
        lig_s, pro_s, W1, b1, bn_gamma, bn_beta, bn_mean, bn_var, Al, At);

    pair_kernel<<<(kM / 256), 256, 0, stream>>>(
        Al, At, W_pi, b_pi, W_sigma, b_sigma, W_mu, b_mu,
        lig_pos, pro_pos, out);
}

// Round 2
// 128.765 us; speedup vs baseline: 1.3747x; 1.3747x over previous
//
#include <hip/hip_runtime.h>
#include <math.h>

// Problem constants
constexpr int kB  = 8;
constexpr int kNL = 48;
constexpr int kNT = 512;
constexpr int kH  = 128;
constexpr int kG  = 10;

constexpr int kRowsL = kB * kNL;          // 384
constexpr int kRowsT = kB * kNT;          // 4096
constexpr int kRows  = kRowsL + kRowsT;   // 4480
constexpr int kM     = kB * kNL * kNT;    // 196608
constexpr float kEps = 1e-5f;

// Output layout (flat concat, reference return order)
constexpr size_t OFF_PI = 0;
constexpr size_t OFF_SG = (size_t)kM * kG;
constexpr size_t OFF_MU = 2 * (size_t)kM * kG;
constexpr size_t OFF_D  = 3 * (size_t)kM * kG;
constexpr size_t OFF_CB = OFF_D + kM;

typedef __attribute__((ext_vector_type(8))) short short8;   // 8 bf16 (4 VGPR)
typedef __attribute__((ext_vector_type(4))) float f32x4;    // MFMA C/D

__device__ __forceinline__ short f2bf(float f) {            // RNE float->bf16
    unsigned u = __builtin_bit_cast(unsigned, f);
    unsigned r = u + 0x7fffu + ((u >> 16) & 1u);
    return (short)(r >> 16);
}
__device__ __forceinline__ float elu_f(float x) {
    return x > 0.0f ? x : (__expf(x) - 1.0f);
}

// ---------------------------------------------------------------------------
// pack: fold BN scale into W1, emit B-fragment-layout bf16 weight images.
//   W1p[kt][nt8][lane][j]  = W1[c][k]*s[c],  c=nt*16+(lane&15), k=kt*32+(lane>>4)*8+j
//   Wcp[kt][nt3][lane][j]  = Wcat[n][k]      (pi|sigma|mu rows, padded to 16 with 0)
//   bias_l[c] = (b1[c]-mean[c])*s[c]+beta[c]
// ---------------------------------------------------------------------------
__global__ __launch_bounds__(256) void pack_kernel(
    const float* __restrict__ W1, const float* __restrict__ b1,
    const float* __restrict__ gamma, const float* __restrict__ beta,
    const float* __restrict__ mean, const float* __restrict__ var,
    const float* __restrict__ Wpi, const float* __restrict__ Wsg,
    const float* __restrict__ Wmu,
    short* __restrict__ W1p, short* __restrict__ Wcp, float* __restrict__ bias_l)
{
    const int tid = threadIdx.x;
    __shared__ float s_s[kH];
    if (tid < kH) {
        float s = gamma[tid] * rsqrtf(var[tid] + kEps);
        s_s[tid] = s;
        bias_l[tid] = (b1[tid] - mean[tid]) * s + beta[tid];
    }
    __syncthreads();

    // W1p: 4 ktiles x 8 ntiles x 64 lanes, 8 bf16 each
    for (int idx = tid; idx < 4 * 8 * 64; idx += 256) {
        const int kt = idx >> 9, nt = (idx >> 6) & 7, lane = idx & 63;
        const int c  = nt * 16 + (lane & 15);
        const int k0 = kt * 32 + (lane >> 4) * 8;
        const float s = s_s[c];
        const float* wr = W1 + (size_t)c * kH + k0;
        short8 v;
#pragma unroll
        for (int j = 0; j < 8; ++j) v[j] = f2bf(wr[j] * s);
        *((short8*)W1p + idx) = v;
    }
    // Wcp: 4 ktiles x 3 ntiles x 64 lanes
    for (int idx = tid; idx < 4 * 3 * 64; idx += 256) {
        const int kt = idx / 192, rem = idx % 192, nt = rem >> 6, lane = rem & 63;
        const int n  = lane & 15;
        const int k0 = kt * 32 + (lane >> 4) * 8;
        const float* W = (nt == 0) ? Wpi : ((nt == 1) ? Wsg : Wmu);
        short8 v;
        if (n < kG) {
            const float* wr = W + (size_t)n * kH + k0;
#pragma unroll
            for (int j = 0; j < 8; ++j) v[j] = f2bf(wr[j]);
        } else {
#pragma unroll
            for (int j = 0; j < 8; ++j) v[j] = 0;
        }
        *((short8*)Wcp + idx) = v;
    }
}

// ---------------------------------------------------------------------------
// prep: [4480x128] @ W1s^T via bf16 MFMA. Rows 0..383 -> Al (+bias), rest -> At.
// Grid: 280 blocks (one 16-row mtile each), 4 waves, wave handles 2 ntiles.
// ---------------------------------------------------------------------------
__global__ __launch_bounds__(256) void prep_mfma(
    const float* __restrict__ lig_s, const float* __restrict__ pro_s,
    const short* __restrict__ W1p, const float* __restrict__ bias_l,
    float* __restrict__ Al, float* __restrict__ At)
{
    const int mtile = blockIdx.x;                 // 0..279
    const int wave = threadIdx.x >> 6, lane = threadIdx.x & 63;
    const int q = lane >> 4, n16 = lane & 15;

    short8 bfrag[2][4];
    const short8* wp = (const short8*)W1p;
#pragma unroll
    for (int kt = 0; kt < 4; ++kt)
#pragma unroll
        for (int h = 0; h < 2; ++h)
            bfrag[h][kt] = wp[(kt * 8 + (2 * wave + h)) * 64 + lane];

    const int row = mtile * 16 + n16;
    const bool lig = (row < kRowsL);              // uniform per block (384=24*16)
    const float* X = lig ? (lig_s + (size_t)row * kH)
                         : (pro_s + (size_t)(row - kRowsL) * kH);

    f32x4 acc[2] = {};
#pragma unroll
    for (int kt = 0; kt < 4; ++kt) {
        const float4* xp = (const float4*)(X + kt * 32 + q * 8);
        float4 x0 = xp[0], x1 = xp[1];
        short8 a;
        a[0] = f2bf(x0.x); a[1] = f2bf(x0.y); a[2] = f2bf(x0.z); a[3] = f2bf(x0.w);
        a[4] = f2bf(x1.x); a[5] = f2bf(x1.y); a[6] = f2bf(x1.z); a[7] = f2bf(x1.w);
        acc[0] = __builtin_amdgcn_mfma_f32_16x16x32_bf16(a, bfrag[0][kt], acc[0], 0, 0, 0);
        acc[1] = __builtin_amdgcn_mfma_f32_16x16x32_bf16(a, bfrag[1][kt], acc[1], 0, 0, 0);
    }

#pragma unroll
    for (int h = 0; h < 2; ++h) {
        const int c = (2 * wave + h) * 16 + n16;
        const float bi = lig ? bias_l[c] : 0.0f;
#pragma unroll
        for (int r = 0; r < 4; ++r) {
            const int R = mtile * 16 + q * 4 + r;
            const float v = acc[h][r] + bi;
            if (lig) Al[(size_t)R * kH + c] = v;
            else     At[(size_t)(R - kRowsL) * kH + c] = v;
        }
    }
}

// ---------------------------------------------------------------------------
// pair: per wave, 32 pairs (2 mtiles) sharing one ligand row.
//   C-frag = bf16(elu(Al[bl]+At[pr])), weights resident as B-frags (48 VGPR).
//   Epilogue: softmax over n (cross-lane within 16-groups), elu+c, stores.
// Grid: 384*4 blocks x 256 thr; block = (bl, 128-t chunk); wave = 32 t's.
// ---------------------------------------------------------------------------
__global__ __launch_bounds__(256) void pair_mfma(
    const float* __restrict__ Al, const float* __restrict__ At,
    const short* __restrict__ Wcp,
    const float* __restrict__ bpi, const float* __restrict__ bsg,
    const float* __restrict__ bmu,
    float* __restrict__ out)
{
    const int blk = blockIdx.x;
    const int bl = blk >> 2, tch = blk & 3;
    const int wave = threadIdx.x >> 6, lane = threadIdx.x & 63;
    const int q = lane >> 4, n = lane & 15;
    const int b = bl / kNL;
    const int t0 = tch * 128 + wave * 32;

    short8 bf[3][4];
    const short8* wp = (const short8*)Wcp;
#pragma unroll
    for (int kt = 0; kt < 4; ++kt)
#pragma unroll
        for (int ntl = 0; ntl < 3; ++ntl)
            bf[ntl][kt] = wp[(kt * 3 + ntl) * 64 + lane];

    const int nc = (n < kG) ? n : (kG - 1);
    const float bias0 = (n < kG) ? bpi[nc] : 0.0f;
    const float bias1 = (n < kG) ? bsg[nc] : 0.0f;
    const float bias2 = (n < kG) ? bmu[nc] : 0.0f;

    const float* alp = Al + (size_t)bl * kH;
    f32x4 acc[2][3] = {};

#pragma unroll
    for (int mt = 0; mt < 2; ++mt) {
        const int t = t0 + mt * 16 + n;
        const float* atp = At + (size_t)(b * kNT + t) * kH;
#pragma unroll
        for (int kt = 0; kt < 4; ++kt) {
            const float4* ap4 = (const float4*)(alp + kt * 32 + q * 8);
            const float4* tp4 = (const float4*)(atp + kt * 32 + q * 8);
            float4 a0 = ap4[0], a1 = ap4[1];
            float4 t0v = tp4[0], t1v = tp4[1];
            short8 a;
            a[0] = f2bf(elu_f(a0.x + t0v.x)); a[1] = f2bf(elu_f(a0.y + t0v.y));
            a[2] = f2bf(elu_f(a0.z + t0v.z)); a[3] = f2bf(elu_f(a0.w + t0v.w));
            a[4] = f2bf(elu_f(a1.x + t1v.x)); a[5] = f2bf(elu_f(a1.y + t1v.y));
            a[6] = f2bf(elu_f(a1.z + t1v.z)); a[7] = f2bf(elu_f(a1.w + t1v.w));
            acc[mt][0] = __builtin_amdgcn_mfma_f32_16x16x32_bf16(a, bf[0][kt], acc[mt][0], 0, 0, 0);
            acc[mt][1] = __builtin_amdgcn_mfma_f32_16x16x32_bf16(a, bf[1][kt], acc[mt][1], 0, 0, 0);
            acc[mt][2] = __builtin_amdgcn_mfma_f32_16x16x32_bf16(a, bf[2][kt], acc[mt][2], 0, 0, 0);
        }
    }

    const int pairbase = bl * kNT + t0;
#pragma unroll
    for (int mt = 0; mt < 2; ++mt) {
        // --- pi: masked softmax across the 16-lane n-group ---
#pragma unroll
        for (int r = 0; r < 4; ++r) {
            const float lg = acc[mt][0][r] + bias0;
            float mx = (n < kG) ? lg : -3.0e38f;
#pragma unroll
            for (int d = 1; d < 16; d <<= 1) mx = fmaxf(mx, __shfl_xor(mx, d));
            const float e = (n < kG) ? __expf(lg - mx) : 0.0f;
            float sm = e;
#pragma unroll
            for (int d = 1; d < 16; d <<= 1) sm += __shfl_xor(sm, d);
            const int m = pairbase + mt * 16 + q * 4 + r;
            if (n < kG) out[OFF_PI + (size_t)m * kG + n] = e / sm;
        }
        // --- sigma / mu ---
#pragma unroll
        for (int r = 0; r < 4; ++r) {
            const int m = pairbase + mt * 16 + q * 4 + r;
            if (n < kG) {
                out[OFF_SG + (size_t)m * kG + n] = elu_f(acc[mt][1][r] + bias1) + 1.1f;
                out[OFF_MU + (size_t)m * kG + n] = elu_f(acc[mt][2][r] + bias2) + 1.0f;
            }
        }
    }
}

// ---------------------------------------------------------------------------
// dist + batch-id (independent of the MLP path)
// ---------------------------------------------------------------------------
__global__ __launch_bounds__(256) void dist_kernel(
    const float* __restrict__ lig_pos, const float* __restrict__ pro_pos,
    float* __restrict__ out)
{
    const int idx = blockIdx.x * 256 + threadIdx.x;  // < kM
    const int bl = idx >> 9, t = idx & 511;
    const int b = bl / kNL;
    const int pr = b * kNT + t;
    const float dx = lig_pos[(size_t)bl * 3 + 0] - pro_pos[(size_t)pr * 3 + 0];
    const float dy = lig_pos[(size_t)bl * 3 + 1] - pro_pos[(size_t)pr * 3 + 1];
    const float dz = lig_pos[(size_t)bl * 3 + 2] - pro_pos[(size_t)pr * 3 + 2];
    out[OFF_D + idx] = sqrtf(dx * dx + dy * dy + dz * dz);
    out[OFF_CB + idx] = (float)b;
}

extern "C" void kernel_launch(void* const* d_in, const int* in_sizes, int n_in,
                              void* d_out, int out_size, void* d_ws, size_t ws_size,
                              hipStream_t stream) {
    (void)in_sizes; (void)n_in; (void)out_size; (void)ws_size;
    const float* lig_s    = (const float*)d_in[0];
    const float* lig_pos  = (const float*)d_in[1];
    const float* pro_s    = (const float*)d_in[3];
    const float* pro_pos  = (const float*)d_in[4];
    const float* W1       = (const float*)d_in[6];
    const float* b1       = (const float*)d_in[7];
    const float* bn_gamma = (const float*)d_in[8];
    const float* bn_beta  = (const float*)d_in[9];
    const float* bn_mean  = (const float*)d_in[10];
    const float* bn_var   = (const float*)d_in[11];
    const float* W_pi     = (const float*)d_in[12];
    const float* b_pi     = (const float*)d_in[13];
    const float* W_sigma  = (const float*)d_in[14];
    const float* b_sigma  = (const float*)d_in[15];
    const float* W_mu     = (const float*)d_in[16];
    const float* b_mu     = (const float*)d_in[17];

    float* out = (float*)d_out;
    float* Al  = (float*)d_ws;                               // 384*128 f32
    float* At  = Al + (size_t)kRowsL * kH;                   // 4096*128 f32
    short* W1p = (short*)(At + (size_t)kRowsT * kH);         // 4*8*64*8 bf16
    short* Wcp = W1p + 4 * 8 * 64 * 8;                       // 4*3*64*8 bf16
    float* bias_l = (float*)(Wcp + 4 * 3 * 64 * 8);          // 128 f32

    pack_kernel<<<1, 256, 0, stream>>>(W1, b1, bn_gamma, bn_beta, bn_mean, bn_var,
                                       W_pi, W_sigma, W_mu, W1p, Wcp, bias_l);
    prep_mfma<<<kRows / 16, 256, 0, stream>>>(lig_s, pro_s, W1p, bias_l, Al, At);
    pair_mfma<<<kRowsL * 4, 256, 0, stream>>>(Al, At, Wcp, b_pi, b_sigma, b_mu, out);
    dist_kernel<<<kM / 256, 256, 0, stream>>>(lig_pos, pro_pos, out);
}